// Round 1
// 899.463 us; speedup vs baseline: 1.0992x; 1.0992x over previous
//
#include <hip/hip_runtime.h>
#include <math.h>

#define HDIM 128
#define TDIM 4096
#define NET_T 8

// ---------------------------------------------------------------------------
// helpers
// ---------------------------------------------------------------------------
__device__ __forceinline__ float wave_sum64(float v) {
#pragma unroll
  for (int d = 32; d > 0; d >>= 1) v += __shfl_xor(v, d, 64);
  return v;
}

__device__ __forceinline__ float gelu_exact(float x) {
  return 0.5f * x * (1.0f + erff(x * 0.70710678118654752440f));
}

struct LN2 { float zx, zy, norm; };

// layer-norm over 128 elements spread 2-per-lane across one 64-lane wave.
// biased variance, eps=1e-5, no affine. norm = ||z||_2 (uniform across lanes).
__device__ __forceinline__ LN2 ln128(float x0, float x1) {
  float s = wave_sum64(x0 + x1);
  float mean = s * (1.0f / 128.0f);
  float d0 = x0 - mean, d1 = x1 - mean;
  float sq = wave_sum64(d0 * d0 + d1 * d1);
  float var = sq * (1.0f / 128.0f);
  float rstd = rsqrtf(var + 1e-5f);
  LN2 r;
  r.zx = d0 * rstd;
  r.zy = d1 * rstd;
  r.norm = sqrtf(sq) * rstd;
  return r;
}

// ---------------------------------------------------------------------------
// K1: per-subgraph counts (target edges; all nodes)
// ---------------------------------------------------------------------------
__global__ void count_kernel(const int* __restrict__ edge_dst,
                             const int* __restrict__ esg,
                             const int* __restrict__ tli,
                             const int* __restrict__ nsg,
                             int* __restrict__ ecnt, int* __restrict__ ncnt,
                             int E_, int N_) {
  int gid = blockIdx.x * blockDim.x + threadIdx.x;
  if (gid < E_) {
    int s = esg[gid];
    if (edge_dst[gid] == tli[s]) atomicAdd(&ecnt[s], 1);
  }
  if (gid < N_) {
    atomicAdd(&ncnt[nsg[gid]], 1);
  }
}

// ---------------------------------------------------------------------------
// K2: exclusive scan of 4096 counts. One 64-lane wave per array.
// ---------------------------------------------------------------------------
__global__ __launch_bounds__(64) void scan_kernel(
    const int* __restrict__ ecnt, int* __restrict__ eoff, int* __restrict__ ecur,
    const int* __restrict__ ncnt, int* __restrict__ noff, int* __restrict__ ncur) {
  const int* cnt;
  int *off, *cur;
  if (blockIdx.x == 0) { cnt = ecnt; off = eoff; cur = ecur; }
  else                 { cnt = ncnt; off = noff; cur = ncur; }
  int lane = threadIdx.x;
  int base = lane * 64;
  int s = 0;
  for (int i = 0; i < 64; i++) s += cnt[base + i];
  int incl = s;
#pragma unroll
  for (int d = 1; d < 64; d <<= 1) {
    int v = __shfl_up(incl, d, 64);
    if (lane >= d) incl += v;
  }
  int run = incl - s;
  for (int i = 0; i < 64; i++) {
    off[base + i] = run;
    cur[base + i] = run;
    run += cnt[base + i];
  }
}

// ---------------------------------------------------------------------------
// K3: scatter target-edge records and node records into per-subgraph buckets
// ---------------------------------------------------------------------------
__global__ void scatter_kernel(const int* __restrict__ edge_dst,
                               const int* __restrict__ esg,
                               const int* __restrict__ tli,
                               const int* __restrict__ edge_src,
                               const int* __restrict__ rel_ids,
                               const float* __restrict__ etime,
                               const int* __restrict__ nsg,
                               const int* __restrict__ depth,
                               int* __restrict__ ecur, int* __restrict__ ncur,
                               int* __restrict__ s_eid, int* __restrict__ s_srcpk,
                               float* __restrict__ s_t, int* __restrict__ s_npk,
                               int E_, int N_) {
  int gid = blockIdx.x * blockDim.x + threadIdx.x;
  if (gid < E_) {
    int sg = esg[gid];
    if (edge_dst[gid] == tli[sg]) {
      int pos = atomicAdd(&ecur[sg], 1);
      s_eid[pos] = gid;
      s_srcpk[pos] = (edge_src[gid] << 1) | (rel_ids[gid] < NET_T ? 1 : 0);
      s_t[pos] = etime[gid];
    }
  }
  if (gid < N_) {
    int sg = nsg[gid];
    int pos = atomicAdd(&ncur[sg], 1);
    s_npk[pos] = (gid << 1) | (depth[gid] == 1 ? 1 : 0);
  }
}

// ---------------------------------------------------------------------------
// K4: 4 waves (256 threads) per target.
//   Phase E: ALL 4 waves split the target-edge list (contiguous chunks).
//   Phase N: ALL 4 waves split the node list.
//   Metadata (eid/pk/t) is preloaded lane-parallel (coalesced) and broadcast
//   via __shfl, so row-gather addresses have no memory dependency. expf is
//   computed once per record at preload time. Scalar sums (denominators,
//   tsum, counts) accumulate at preload time + one wave reduction.
//   Partials -> LDS, wave 0 combines, does 8 layer-norms + epilogue.
//   Norms go to a per-target buffer (no global atomics).
// Each lane owns columns 2*lane, 2*lane+1 of H=128.
// ---------------------------------------------------------------------------
__global__ __launch_bounds__(256) void target_kernel(
    const float* __restrict__ node_repr, const float* __restrict__ edge_repr,
    const int* __restrict__ eoff, const int* __restrict__ ecnt,
    const int* __restrict__ noff, const int* __restrict__ ncnt,
    const int* __restrict__ s_eid, const int* __restrict__ s_srcpk,
    const float* __restrict__ s_t, const int* __restrict__ s_npk,
    const float* __restrict__ W1, const float* __restrict__ b1,
    float* __restrict__ fused, float* __restrict__ normbuf) {
  const int t = blockIdx.x;
  const int tid = threadIdx.x;
  const int w = tid >> 6;
  const int lane = tid & 63;
  const int e0 = eoff[t], ec = ecnt[t];
  const int n0 = noff[t], nc = ncnt[t];
  const int co = 2 * lane;

  __shared__ float lse[4][6][128];  // per wave: ais, aos, ail, aol, hs, hl
  __shared__ float lss[4][6];       // per wave: d_is,d_os,d_il,d_ol,tsum,cin
  __shared__ float lsn[4][2][128];  // per wave: h1, h2
  __shared__ float lnc[4];          // per wave: c1

  // ---- phase E: edges, balanced across all 4 waves ----
  {
    const int cbeg = e0 + ((ec * w) >> 2);
    const int cend = e0 + ((ec * (w + 1)) >> 2);
    float ais0 = 0, ais1 = 0, aos0 = 0, aos1 = 0;
    float ail0 = 0, ail1 = 0, aol0 = 0, aol1 = 0;
    float hs0 = 0, hs1 = 0, hl0 = 0, hl1 = 0;
    float d_is = 0, d_os = 0, d_il = 0, d_ol = 0, tsum = 0, cin = 0;

    for (int base = cbeg; base < cend; base += 64) {
      int n = cend - base;
      if (n > 64) n = 64;
      int p_eid = 0, p_pk = 0;
      float p_sw = 0.0f, p_lw = 0.0f;
      if (lane < n) {
        int idx = base + lane;
        p_eid = s_eid[idx];
        p_pk = s_srcpk[idx];
        float tt = s_t[idx];
        p_sw = expf(-tt);
        p_lw = expf(-tt * (1.0f / 24.0f));
        float fin = (float)(p_pk & 1);
        float wis = fin * p_sw, wil = fin * p_lw;
        d_is += wis; d_os += p_sw - wis;
        d_il += wil; d_ol += p_lw - wil;
        tsum += tt; cin += fin;
      }
#pragma unroll 2
      for (int j = 0; j < n; ++j) {
        int eid = __shfl(p_eid, j, 64);
        int pk = __shfl(p_pk, j, 64);
        float sw = __shfl(p_sw, j, 64);
        float lw = __shfl(p_lw, j, 64);
        int src = pk >> 1;
        float fin = (float)(pk & 1);
        const float2 er = *(const float2*)(edge_repr + (size_t)eid * HDIM + co);
        const float2 nr = *(const float2*)(node_repr + (size_t)src * HDIM + co);
        float wis = fin * sw, wos = sw - wis;
        float wil = fin * lw, wol = lw - wil;
        ais0 = fmaf(er.x, wis, ais0); ais1 = fmaf(er.y, wis, ais1);
        aos0 = fmaf(er.x, wos, aos0); aos1 = fmaf(er.y, wos, aos1);
        ail0 = fmaf(er.x, wil, ail0); ail1 = fmaf(er.y, wil, ail1);
        aol0 = fmaf(er.x, wol, aol0); aol1 = fmaf(er.y, wol, aol1);
        hs0 = fmaf(nr.x, sw, hs0); hs1 = fmaf(nr.y, sw, hs1);
        hl0 = fmaf(nr.x, lw, hl0); hl1 = fmaf(nr.y, lw, hl1);
      }
    }
    lse[w][0][co] = ais0; lse[w][0][co + 1] = ais1;
    lse[w][1][co] = aos0; lse[w][1][co + 1] = aos1;
    lse[w][2][co] = ail0; lse[w][2][co + 1] = ail1;
    lse[w][3][co] = aol0; lse[w][3][co + 1] = aol1;
    lse[w][4][co] = hs0;  lse[w][4][co + 1] = hs1;
    lse[w][5][co] = hl0;  lse[w][5][co + 1] = hl1;
    d_is = wave_sum64(d_is); d_os = wave_sum64(d_os);
    d_il = wave_sum64(d_il); d_ol = wave_sum64(d_ol);
    tsum = wave_sum64(tsum); cin = wave_sum64(cin);
    if (lane == 0) {
      lss[w][0] = d_is; lss[w][1] = d_os; lss[w][2] = d_il;
      lss[w][3] = d_ol; lss[w][4] = tsum; lss[w][5] = cin;
    }
  }

  // ---- phase N: nodes, balanced across all 4 waves ----
  {
    const int cbeg = n0 + ((nc * w) >> 2);
    const int cend = n0 + ((nc * (w + 1)) >> 2);
    float h10 = 0, h11 = 0, h20 = 0, h21 = 0, c1 = 0;

    for (int base = cbeg; base < cend; base += 64) {
      int n = cend - base;
      if (n > 64) n = 64;
      int p_pk = 0;
      if (lane < n) {
        p_pk = s_npk[base + lane];
        c1 += (float)(p_pk & 1);
      }
#pragma unroll 2
      for (int j = 0; j < n; ++j) {
        int pk = __shfl(p_pk, j, 64);
        int idx = pk >> 1;
        float f1 = (float)(pk & 1);
        float f2 = 1.0f - f1;
        const float2 nr = *(const float2*)(node_repr + (size_t)idx * HDIM + co);
        h10 = fmaf(nr.x, f1, h10); h11 = fmaf(nr.y, f1, h11);
        h20 = fmaf(nr.x, f2, h20); h21 = fmaf(nr.y, f2, h21);
      }
    }
    lsn[w][0][co] = h10; lsn[w][0][co + 1] = h11;
    lsn[w][1][co] = h20; lsn[w][1][co + 1] = h21;
    c1 = wave_sum64(c1);
    if (lane == 0) lnc[w] = c1;
  }

  __syncthreads();
  if (w != 0) return;

  // ---- wave 0: combine 4 partials + epilogue ----
  float v0[6], v1[6];
#pragma unroll
  for (int k = 0; k < 6; ++k) {
    v0[k] = lse[0][k][co] + lse[1][k][co] + lse[2][k][co] + lse[3][k][co];
    v1[k] = lse[0][k][co + 1] + lse[1][k][co + 1] + lse[2][k][co + 1] + lse[3][k][co + 1];
  }
  float dsc[6];
#pragma unroll
  for (int k = 0; k < 6; ++k)
    dsc[k] = lss[0][k] + lss[1][k] + lss[2][k] + lss[3][k];
  float h10 = lsn[0][0][co] + lsn[1][0][co] + lsn[2][0][co] + lsn[3][0][co];
  float h11 = lsn[0][0][co + 1] + lsn[1][0][co + 1] + lsn[2][0][co + 1] + lsn[3][0][co + 1];
  float h20 = lsn[0][1][co] + lsn[1][1][co] + lsn[2][1][co] + lsn[3][1][co];
  float h21 = lsn[0][1][co + 1] + lsn[1][1][co + 1] + lsn[2][1][co + 1] + lsn[3][1][co + 1];
  float c1 = lnc[0] + lnc[1] + lnc[2] + lnc[3];
  float c2 = (float)nc - c1;

  float d_is = dsc[0], d_os = dsc[1], d_il = dsc[2], d_ol = dsc[3];
  float tsum = dsc[4], cin = dsc[5];

  float r_is = 1.0f / fmaxf(d_is, 1e-6f);
  float r_os = 1.0f / fmaxf(d_os, 1e-6f);
  float r_il = 1.0f / fmaxf(d_il, 1e-6f);
  float r_ol = 1.0f / fmaxf(d_ol, 1e-6f);
  float sm = d_is + d_os;
  float lm = d_il + d_ol;
  float r_sm = 1.0f / fmaxf(sm, 1e-6f);
  float r_lm = 1.0f / fmaxf(lm, 1e-6f);
  float r_c1 = 1.0f / fmaxf(c1, 1e-6f);
  float r_c2 = 1.0f / fmaxf(c2, 1e-6f);

  float mis0 = v0[0] * r_is, mis1 = v1[0] * r_is;
  float mos0 = v0[1] * r_os, mos1 = v1[1] * r_os;
  float mil0 = v0[2] * r_il, mil1 = v1[2] * r_il;
  float mol0 = v0[3] * r_ol, mol1 = v1[3] * r_ol;
  float mhs0 = v0[4] * r_sm, mhs1 = v1[4] * r_sm;
  float mhl0 = v0[5] * r_lm, mhl1 = v1[5] * r_lm;
  float mh10 = h10 * r_c1, mh11 = h11 * r_c1;
  float mh20 = h20 * r_c2, mh21 = h21 * r_c2;

  LN2 z_burst = ln128(mis0 + mos0 - mil0 - mol0, mis1 + mos1 - mil1 - mol1);
  LN2 z_dgap  = ln128(mol0 - mil0, mol1 - mil1);
  LN2 z_hgap  = ln128(mh10 - mh20, mh11 - mh21);
  LN2 z_sl    = ln128(mhs0 - mhl0, mhs1 - mhl1);
  LN2 z_asym  = ln128(fabsf(z_dgap.zx), fabsf(z_dgap.zy));
  LN2 z_h1    = ln128(mh10, mh11);
  LN2 z_h2    = ln128(mh20, mh21);
  LN2 z_rb    = ln128(mil0 + mol0, mil1 + mol1);

  if (lane == 0) {
    normbuf[t] = z_hgap.norm;
    normbuf[TDIM + t] = z_sl.norm;
    normbuf[2 * TDIM + t] = z_dgap.norm;
  }

  float* frow = fused + (size_t)t * 1056;
  *(float2*)(frow + 0 * HDIM + co) = make_float2(z_burst.zx, z_burst.zy);
  *(float2*)(frow + 1 * HDIM + co) = make_float2(z_dgap.zx, z_dgap.zy);
  *(float2*)(frow + 2 * HDIM + co) = make_float2(z_hgap.zx, z_hgap.zy);
  *(float2*)(frow + 3 * HDIM + co) = make_float2(z_sl.zx, z_sl.zy);
  *(float2*)(frow + 4 * HDIM + co) = make_float2(z_asym.zx, z_asym.zy);
  *(float2*)(frow + 5 * HDIM + co) = make_float2(z_h1.zx, z_h1.zy);
  *(float2*)(frow + 6 * HDIM + co) = make_float2(z_h2.zx, z_h2.zy);
  *(float2*)(frow + 7 * HDIM + co) = make_float2(z_rb.zx, z_rb.zy);

  float ecf = (float)ec;
  float sf[8];
  sf[0] = log1pf(cin);
  sf[1] = log1pf(ecf - cin);
  sf[2] = log1pf(c1);
  sf[3] = log1pf(c2);
  sf[4] = tsum / fmaxf(ecf, 1e-6f);
  sf[5] = sm;
  sf[6] = lm;
  sf[7] = sm - lm;
  if (lane < 32) {
    float acc = b1[lane];
#pragma unroll
    for (int i = 0; i < 8; i++) acc += sf[i] * W1[i * 32 + lane];
    frow[1024 + lane] = gelu_exact(acc);
  }
}

// ---------------------------------------------------------------------------
// K5/K6: tiled fp32 GEMM  C[M,N] = epilogue(A[M,K] @ B[K,N] + bias)
// 32x64 tile, BK=32, 256 threads, 2x4 per-thread microtile.
// MODE 0: exact GELU. MODE 1: 0.25*tanh.
// ---------------------------------------------------------------------------
template <int MODE>
__global__ __launch_bounds__(256) void gemm_kernel(
    const float* __restrict__ A, const float* __restrict__ B,
    const float* __restrict__ bias, float* __restrict__ C,
    int M, int N, int K) {
  __shared__ __align__(16) float As[32][34];  // [k][m]
  __shared__ __align__(16) float Bs[32][68];  // [k][n]
  const int tid = threadIdx.x;
  const int tx = tid & 15, ty = tid >> 4;
  const int m0 = blockIdx.y * 32, n0 = blockIdx.x * 64;
  float acc[2][4] = {};

  const int am = tid >> 3;            // 0..31
  const int ak = (tid & 7) * 4;       // 0,4,..,28
  const int bk = tid >> 3;            // 0..31
  const int bn = (tid & 7) * 8;       // 0,8,..,56

  for (int kt = 0; kt < K; kt += 32) {
    float4 av = *(const float4*)&A[(size_t)(m0 + am) * K + kt + ak];
    const float* bp = &B[(size_t)(kt + bk) * N + n0 + bn];
    float4 bv0 = *(const float4*)bp;
    float4 bv1 = *(const float4*)(bp + 4);
    As[ak + 0][am] = av.x;
    As[ak + 1][am] = av.y;
    As[ak + 2][am] = av.z;
    As[ak + 3][am] = av.w;
    *(float4*)&Bs[bk][bn] = bv0;
    *(float4*)&Bs[bk][bn + 4] = bv1;
    __syncthreads();
#pragma unroll
    for (int kk = 0; kk < 32; kk++) {
      float2 a2 = *(const float2*)&As[kk][ty * 2];
      float4 b4 = *(const float4*)&Bs[kk][tx * 4];
      float a[2] = {a2.x, a2.y};
      float b[4] = {b4.x, b4.y, b4.z, b4.w};
#pragma unroll
      for (int i2 = 0; i2 < 2; i2++)
#pragma unroll
        for (int j2 = 0; j2 < 4; j2++)
          acc[i2][j2] = fmaf(a[i2], b[j2], acc[i2][j2]);
    }
    __syncthreads();
  }

#pragma unroll
  for (int i2 = 0; i2 < 2; i2++) {
    int m = m0 + ty * 2 + i2;
    int n = n0 + tx * 4;
    float4 bb = *(const float4*)&bias[n];
    float4 v;
    v.x = acc[i2][0] + bb.x;
    v.y = acc[i2][1] + bb.y;
    v.z = acc[i2][2] + bb.z;
    v.w = acc[i2][3] + bb.w;
    if (MODE == 0) {
      v.x = gelu_exact(v.x); v.y = gelu_exact(v.y);
      v.z = gelu_exact(v.z); v.w = gelu_exact(v.w);
    } else {
      v.x = 0.25f * tanhf(v.x); v.y = 0.25f * tanhf(v.y);
      v.z = 0.25f * tanhf(v.z); v.w = 0.25f * tanhf(v.w);
    }
    *(float4*)&C[(size_t)m * N + n] = v;
  }
}

// ---------------------------------------------------------------------------
// K7: tree-reduce per-target norms -> output tail (replaces global atomics)
// ---------------------------------------------------------------------------
__global__ __launch_bounds__(256) void finalize_kernel(
    const float* __restrict__ normbuf, float* __restrict__ out) {
  const int tid = threadIdx.x;
  const int w = tid >> 6, lane = tid & 63;
  float s0 = 0, s1 = 0, s2 = 0;
  for (int t = tid; t < TDIM; t += 256) {
    s0 += normbuf[t];
    s1 += normbuf[TDIM + t];
    s2 += normbuf[2 * TDIM + t];
  }
  s0 = wave_sum64(s0);
  s1 = wave_sum64(s1);
  s2 = wave_sum64(s2);
  __shared__ float red[3][4];
  if (lane == 0) { red[0][w] = s0; red[1][w] = s1; red[2][w] = s2; }
  __syncthreads();
  if (tid < 3) {
    float v = red[tid][0] + red[tid][1] + red[tid][2] + red[tid][3];
    out[(size_t)TDIM * HDIM + tid] = v * (1.0f / (float)TDIM);
  }
}

// ---------------------------------------------------------------------------
extern "C" void kernel_launch(void* const* d_in, const int* in_sizes, int n_in,
                              void* d_out, int out_size, void* d_ws, size_t ws_size,
                              hipStream_t stream) {
  const float* node_repr = (const float*)d_in[0];
  const float* edge_repr = (const float*)d_in[1];
  const int* edge_src = (const int*)d_in[2];
  const int* edge_dst = (const int*)d_in[3];
  const int* rel_ids = (const int*)d_in[4];
  const float* etime = (const float*)d_in[5];
  const int* tli = (const int*)d_in[6];
  const int* nsg = (const int*)d_in[7];
  const int* esg = (const int*)d_in[8];
  const int* depth = (const int*)d_in[9];
  const float* W1 = (const float*)d_in[10];
  const float* b1 = (const float*)d_in[11];
  const float* W2 = (const float*)d_in[12];
  const float* b2 = (const float*)d_in[13];
  const float* W3 = (const float*)d_in[14];
  const float* b3 = (const float*)d_in[15];
  float* out = (float*)d_out;

  const int E_ = in_sizes[2];
  const int N_ = in_sizes[7];

  char* ws = (char*)d_ws;
  size_t off = 0;
  auto alloc = [&](size_t bytes) -> void* {
    off = (off + 255) & ~(size_t)255;
    void* p = ws + off;
    off += bytes;
    return p;
  };
  int* ecnt = (int*)alloc((size_t)TDIM * 4);
  int* eoff = (int*)alloc((size_t)TDIM * 4);
  int* ecur = (int*)alloc((size_t)TDIM * 4);
  int* ncnt = (int*)alloc((size_t)TDIM * 4);
  int* noff = (int*)alloc((size_t)TDIM * 4);
  int* ncur = (int*)alloc((size_t)TDIM * 4);
  int* s_eid = (int*)alloc((size_t)E_ * 4);
  int* s_srcpk = (int*)alloc((size_t)E_ * 4);
  float* s_t = (float*)alloc((size_t)E_ * 4);
  int* s_npk = (int*)alloc((size_t)N_ * 4);
  float* fused = (float*)alloc((size_t)TDIM * 1056 * 4);
  float* hidden = (float*)alloc((size_t)TDIM * 256 * 4);
  float* normbuf = (float*)alloc((size_t)3 * TDIM * 4);

  hipMemsetAsync(ecnt, 0, (size_t)TDIM * 4, stream);
  hipMemsetAsync(ncnt, 0, (size_t)TDIM * 4, stream);

  int gmax = (E_ > N_ ? E_ : N_);
  int g1 = (gmax + 255) / 256;

  count_kernel<<<g1, 256, 0, stream>>>(edge_dst, esg, tli, nsg, ecnt, ncnt, E_, N_);
  scan_kernel<<<2, 64, 0, stream>>>(ecnt, eoff, ecur, ncnt, noff, ncur);
  scatter_kernel<<<g1, 256, 0, stream>>>(edge_dst, esg, tli, edge_src, rel_ids,
                                         etime, nsg, depth, ecur, ncur,
                                         s_eid, s_srcpk, s_t, s_npk, E_, N_);
  target_kernel<<<TDIM, 256, 0, stream>>>(node_repr, edge_repr, eoff, ecnt, noff,
                                          ncnt, s_eid, s_srcpk, s_t, s_npk,
                                          W1, b1, fused, normbuf);
  gemm_kernel<0><<<dim3(256 / 64, TDIM / 32), 256, 0, stream>>>(
      fused, W2, b2, hidden, TDIM, 256, 8 * HDIM + 32);
  gemm_kernel<1><<<dim3(HDIM / 64, TDIM / 32), 256, 0, stream>>>(
      hidden, W3, b3, out, TDIM, HDIM, 256);
  finalize_kernel<<<1, 256, 0, stream>>>(normbuf, out);
}

// Round 2
// 886.887 us; speedup vs baseline: 1.1148x; 1.0142x over previous
//
#include <hip/hip_runtime.h>
#include <math.h>

#define HDIM 128
#define TDIM 4096
#define NET_T 8

// ---------------------------------------------------------------------------
// helpers
// ---------------------------------------------------------------------------
__device__ __forceinline__ float wave_sum64(float v) {
#pragma unroll
  for (int d = 32; d > 0; d >>= 1) v += __shfl_xor(v, d, 64);
  return v;
}

__device__ __forceinline__ float gelu_exact(float x) {
  return 0.5f * x * (1.0f + erff(x * 0.70710678118654752440f));
}

struct LN2 { float zx, zy, norm; };

// layer-norm over 128 elements spread 2-per-lane across one 64-lane wave.
// biased variance, eps=1e-5, no affine. norm = ||z||_2 (uniform across lanes).
__device__ __forceinline__ LN2 ln128(float x0, float x1) {
  float s = wave_sum64(x0 + x1);
  float mean = s * (1.0f / 128.0f);
  float d0 = x0 - mean, d1 = x1 - mean;
  float sq = wave_sum64(d0 * d0 + d1 * d1);
  float var = sq * (1.0f / 128.0f);
  float rstd = rsqrtf(var + 1e-5f);
  LN2 r;
  r.zx = d0 * rstd;
  r.zy = d1 * rstd;
  r.norm = sqrtf(sq) * rstd;
  return r;
}

// ---------------------------------------------------------------------------
// K1: per-subgraph counts (target edges; all nodes)
// ---------------------------------------------------------------------------
__global__ void count_kernel(const int* __restrict__ edge_dst,
                             const int* __restrict__ esg,
                             const int* __restrict__ tli,
                             const int* __restrict__ nsg,
                             int* __restrict__ ecnt, int* __restrict__ ncnt,
                             int E_, int N_) {
  int gid = blockIdx.x * blockDim.x + threadIdx.x;
  if (gid < E_) {
    int s = esg[gid];
    if (edge_dst[gid] == tli[s]) atomicAdd(&ecnt[s], 1);
  }
  if (gid < N_) {
    atomicAdd(&ncnt[nsg[gid]], 1);
  }
}

// ---------------------------------------------------------------------------
// K2: exclusive scan of 4096 counts. One 64-lane wave per array.
// ---------------------------------------------------------------------------
__global__ __launch_bounds__(64) void scan_kernel(
    const int* __restrict__ ecnt, int* __restrict__ eoff, int* __restrict__ ecur,
    const int* __restrict__ ncnt, int* __restrict__ noff, int* __restrict__ ncur) {
  const int* cnt;
  int *off, *cur;
  if (blockIdx.x == 0) { cnt = ecnt; off = eoff; cur = ecur; }
  else                 { cnt = ncnt; off = noff; cur = ncur; }
  int lane = threadIdx.x;
  int base = lane * 64;
  int s = 0;
  for (int i = 0; i < 64; i++) s += cnt[base + i];
  int incl = s;
#pragma unroll
  for (int d = 1; d < 64; d <<= 1) {
    int v = __shfl_up(incl, d, 64);
    if (lane >= d) incl += v;
  }
  int run = incl - s;
  for (int i = 0; i < 64; i++) {
    off[base + i] = run;
    cur[base + i] = run;
    run += cnt[base + i];
  }
}

// ---------------------------------------------------------------------------
// K3: scatter target-edge records and node records into per-subgraph buckets
// ---------------------------------------------------------------------------
__global__ void scatter_kernel(const int* __restrict__ edge_dst,
                               const int* __restrict__ esg,
                               const int* __restrict__ tli,
                               const int* __restrict__ edge_src,
                               const int* __restrict__ rel_ids,
                               const float* __restrict__ etime,
                               const int* __restrict__ nsg,
                               const int* __restrict__ depth,
                               int* __restrict__ ecur, int* __restrict__ ncur,
                               int* __restrict__ s_eid, int* __restrict__ s_srcpk,
                               float* __restrict__ s_t, int* __restrict__ s_npk,
                               int E_, int N_) {
  int gid = blockIdx.x * blockDim.x + threadIdx.x;
  if (gid < E_) {
    int sg = esg[gid];
    if (edge_dst[gid] == tli[sg]) {
      int pos = atomicAdd(&ecur[sg], 1);
      s_eid[pos] = gid;
      s_srcpk[pos] = (edge_src[gid] << 1) | (rel_ids[gid] < NET_T ? 1 : 0);
      s_t[pos] = etime[gid];
    }
  }
  if (gid < N_) {
    int sg = nsg[gid];
    int pos = atomicAdd(&ncur[sg], 1);
    s_npk[pos] = (gid << 1) | (depth[gid] == 1 ? 1 : 0);
  }
}

// ---------------------------------------------------------------------------
// K4: 4 waves (256 threads) per target.
//   Each wave splits into two 32-lane halves; each lane owns 4 columns
//   (float4, 16B/lane). One load instruction moves TWO 512B rows (records
//   j and j+1), via per-lane shfl source index j + (lane>>5). Halves merge
//   with shfl_xor(32) at phase end. Metadata preloaded lane-parallel;
//   expf once per record; scalar sums at preload + wave reduction.
//   Partials -> LDS, wave 0 combines, does 8 layer-norms + epilogue.
// ---------------------------------------------------------------------------
__global__ __launch_bounds__(256) void target_kernel(
    const float* __restrict__ node_repr, const float* __restrict__ edge_repr,
    const int* __restrict__ eoff, const int* __restrict__ ecnt,
    const int* __restrict__ noff, const int* __restrict__ ncnt,
    const int* __restrict__ s_eid, const int* __restrict__ s_srcpk,
    const float* __restrict__ s_t, const int* __restrict__ s_npk,
    const float* __restrict__ W1, const float* __restrict__ b1,
    float* __restrict__ fused, float* __restrict__ normbuf) {
  const int t = blockIdx.x;
  const int tid = threadIdx.x;
  const int w = tid >> 6;
  const int lane = tid & 63;
  const int e0 = eoff[t], ec = ecnt[t];
  const int n0 = noff[t], nc = ncnt[t];
  const int half = lane >> 5;
  const int l31 = lane & 31;
  const int co4 = 4 * l31;
  const int co = 2 * lane;

  __shared__ __align__(16) float lse[4][6][128];  // ais, aos, ail, aol, hs, hl
  __shared__ float lss[4][6];                     // d_is,d_os,d_il,d_ol,tsum,cin
  __shared__ __align__(16) float lsn[4][2][128];  // h1, h2
  __shared__ float lnc[4];                        // c1

  // ---- phase E: edges, balanced across all 4 waves, 2 records per step ----
  {
    const int cbeg = e0 + ((ec * w) >> 2);
    const int cend = e0 + ((ec * (w + 1)) >> 2);
    float4 ais = {0, 0, 0, 0}, aos = {0, 0, 0, 0};
    float4 ail = {0, 0, 0, 0}, aol = {0, 0, 0, 0};
    float4 hs = {0, 0, 0, 0}, hl = {0, 0, 0, 0};
    float d_is = 0, d_os = 0, d_il = 0, d_ol = 0, tsum = 0, cin = 0;

    for (int base = cbeg; base < cend; base += 64) {
      int n = cend - base;
      if (n > 64) n = 64;
      int p_eid = 0, p_pk = 0;
      float p_sw = 0.0f, p_lw = 0.0f;
      if (lane < n) {
        int idx = base + lane;
        p_eid = s_eid[idx];
        p_pk = s_srcpk[idx];
        float tt = s_t[idx];
        p_sw = expf(-tt);
        p_lw = expf(-tt * (1.0f / 24.0f));
        float fin = (float)(p_pk & 1);
        float wis = fin * p_sw, wil = fin * p_lw;
        d_is += wis; d_os += p_sw - wis;
        d_il += wil; d_ol += p_lw - wil;
        tsum += tt; cin += fin;
      }
#pragma unroll 2
      for (int j = 0; j < n; j += 2) {
        int idx = j + half;
        bool valid = idx < n;
        int srcl = valid ? idx : j;
        int eid = __shfl(p_eid, srcl, 64);
        int pk = __shfl(p_pk, srcl, 64);
        float sw = __shfl(p_sw, srcl, 64);
        float lw = __shfl(p_lw, srcl, 64);
        sw = valid ? sw : 0.0f;
        lw = valid ? lw : 0.0f;
        int src = pk >> 1;
        float fin = (float)(pk & 1);
        const float4 er = *(const float4*)(edge_repr + (size_t)eid * HDIM + co4);
        const float4 nr = *(const float4*)(node_repr + (size_t)src * HDIM + co4);
        float wis = fin * sw, wos = sw - wis;
        float wil = fin * lw, wol = lw - wil;
        ais.x = fmaf(er.x, wis, ais.x); ais.y = fmaf(er.y, wis, ais.y);
        ais.z = fmaf(er.z, wis, ais.z); ais.w = fmaf(er.w, wis, ais.w);
        aos.x = fmaf(er.x, wos, aos.x); aos.y = fmaf(er.y, wos, aos.y);
        aos.z = fmaf(er.z, wos, aos.z); aos.w = fmaf(er.w, wos, aos.w);
        ail.x = fmaf(er.x, wil, ail.x); ail.y = fmaf(er.y, wil, ail.y);
        ail.z = fmaf(er.z, wil, ail.z); ail.w = fmaf(er.w, wil, ail.w);
        aol.x = fmaf(er.x, wol, aol.x); aol.y = fmaf(er.y, wol, aol.y);
        aol.z = fmaf(er.z, wol, aol.z); aol.w = fmaf(er.w, wol, aol.w);
        hs.x = fmaf(nr.x, sw, hs.x); hs.y = fmaf(nr.y, sw, hs.y);
        hs.z = fmaf(nr.z, sw, hs.z); hs.w = fmaf(nr.w, sw, hs.w);
        hl.x = fmaf(nr.x, lw, hl.x); hl.y = fmaf(nr.y, lw, hl.y);
        hl.z = fmaf(nr.z, lw, hl.z); hl.w = fmaf(nr.w, lw, hl.w);
      }
    }
    // merge halves (both halves hold partials for the same 4 columns)
    ais.x += __shfl_xor(ais.x, 32, 64); ais.y += __shfl_xor(ais.y, 32, 64);
    ais.z += __shfl_xor(ais.z, 32, 64); ais.w += __shfl_xor(ais.w, 32, 64);
    aos.x += __shfl_xor(aos.x, 32, 64); aos.y += __shfl_xor(aos.y, 32, 64);
    aos.z += __shfl_xor(aos.z, 32, 64); aos.w += __shfl_xor(aos.w, 32, 64);
    ail.x += __shfl_xor(ail.x, 32, 64); ail.y += __shfl_xor(ail.y, 32, 64);
    ail.z += __shfl_xor(ail.z, 32, 64); ail.w += __shfl_xor(ail.w, 32, 64);
    aol.x += __shfl_xor(aol.x, 32, 64); aol.y += __shfl_xor(aol.y, 32, 64);
    aol.z += __shfl_xor(aol.z, 32, 64); aol.w += __shfl_xor(aol.w, 32, 64);
    hs.x += __shfl_xor(hs.x, 32, 64); hs.y += __shfl_xor(hs.y, 32, 64);
    hs.z += __shfl_xor(hs.z, 32, 64); hs.w += __shfl_xor(hs.w, 32, 64);
    hl.x += __shfl_xor(hl.x, 32, 64); hl.y += __shfl_xor(hl.y, 32, 64);
    hl.z += __shfl_xor(hl.z, 32, 64); hl.w += __shfl_xor(hl.w, 32, 64);
    if (half == 0) {
      *(float4*)&lse[w][0][co4] = ais;
      *(float4*)&lse[w][1][co4] = aos;
      *(float4*)&lse[w][2][co4] = ail;
      *(float4*)&lse[w][3][co4] = aol;
      *(float4*)&lse[w][4][co4] = hs;
      *(float4*)&lse[w][5][co4] = hl;
    }
    d_is = wave_sum64(d_is); d_os = wave_sum64(d_os);
    d_il = wave_sum64(d_il); d_ol = wave_sum64(d_ol);
    tsum = wave_sum64(tsum); cin = wave_sum64(cin);
    if (lane == 0) {
      lss[w][0] = d_is; lss[w][1] = d_os; lss[w][2] = d_il;
      lss[w][3] = d_ol; lss[w][4] = tsum; lss[w][5] = cin;
    }
  }

  // ---- phase N: nodes, balanced across all 4 waves, 2 records per step ----
  {
    const int cbeg = n0 + ((nc * w) >> 2);
    const int cend = n0 + ((nc * (w + 1)) >> 2);
    float4 h1 = {0, 0, 0, 0}, h2 = {0, 0, 0, 0};
    float c1 = 0;

    for (int base = cbeg; base < cend; base += 64) {
      int n = cend - base;
      if (n > 64) n = 64;
      int p_pk = 0;
      if (lane < n) {
        p_pk = s_npk[base + lane];
        c1 += (float)(p_pk & 1);
      }
#pragma unroll 2
      for (int j = 0; j < n; j += 2) {
        int idx = j + half;
        bool valid = idx < n;
        int srcl = valid ? idx : j;
        int pk = __shfl(p_pk, srcl, 64);
        int nidx = pk >> 1;
        float f1 = valid ? (float)(pk & 1) : 0.0f;
        float f2 = valid ? 1.0f - (float)(pk & 1) : 0.0f;
        const float4 nr = *(const float4*)(node_repr + (size_t)nidx * HDIM + co4);
        h1.x = fmaf(nr.x, f1, h1.x); h1.y = fmaf(nr.y, f1, h1.y);
        h1.z = fmaf(nr.z, f1, h1.z); h1.w = fmaf(nr.w, f1, h1.w);
        h2.x = fmaf(nr.x, f2, h2.x); h2.y = fmaf(nr.y, f2, h2.y);
        h2.z = fmaf(nr.z, f2, h2.z); h2.w = fmaf(nr.w, f2, h2.w);
      }
    }
    h1.x += __shfl_xor(h1.x, 32, 64); h1.y += __shfl_xor(h1.y, 32, 64);
    h1.z += __shfl_xor(h1.z, 32, 64); h1.w += __shfl_xor(h1.w, 32, 64);
    h2.x += __shfl_xor(h2.x, 32, 64); h2.y += __shfl_xor(h2.y, 32, 64);
    h2.z += __shfl_xor(h2.z, 32, 64); h2.w += __shfl_xor(h2.w, 32, 64);
    if (half == 0) {
      *(float4*)&lsn[w][0][co4] = h1;
      *(float4*)&lsn[w][1][co4] = h2;
    }
    c1 = wave_sum64(c1);
    if (lane == 0) lnc[w] = c1;
  }

  __syncthreads();
  if (w != 0) return;

  // ---- wave 0: combine 4 partials + epilogue ----
  float v0[6], v1[6];
#pragma unroll
  for (int k = 0; k < 6; ++k) {
    v0[k] = lse[0][k][co] + lse[1][k][co] + lse[2][k][co] + lse[3][k][co];
    v1[k] = lse[0][k][co + 1] + lse[1][k][co + 1] + lse[2][k][co + 1] + lse[3][k][co + 1];
  }
  float dsc[6];
#pragma unroll
  for (int k = 0; k < 6; ++k)
    dsc[k] = lss[0][k] + lss[1][k] + lss[2][k] + lss[3][k];
  float h10 = lsn[0][0][co] + lsn[1][0][co] + lsn[2][0][co] + lsn[3][0][co];
  float h11 = lsn[0][0][co + 1] + lsn[1][0][co + 1] + lsn[2][0][co + 1] + lsn[3][0][co + 1];
  float h20 = lsn[0][1][co] + lsn[1][1][co] + lsn[2][1][co] + lsn[3][1][co];
  float h21 = lsn[0][1][co + 1] + lsn[1][1][co + 1] + lsn[2][1][co + 1] + lsn[3][1][co + 1];
  float c1 = lnc[0] + lnc[1] + lnc[2] + lnc[3];
  float c2 = (float)nc - c1;

  float d_is = dsc[0], d_os = dsc[1], d_il = dsc[2], d_ol = dsc[3];
  float tsum = dsc[4], cin = dsc[5];

  float r_is = 1.0f / fmaxf(d_is, 1e-6f);
  float r_os = 1.0f / fmaxf(d_os, 1e-6f);
  float r_il = 1.0f / fmaxf(d_il, 1e-6f);
  float r_ol = 1.0f / fmaxf(d_ol, 1e-6f);
  float sm = d_is + d_os;
  float lm = d_il + d_ol;
  float r_sm = 1.0f / fmaxf(sm, 1e-6f);
  float r_lm = 1.0f / fmaxf(lm, 1e-6f);
  float r_c1 = 1.0f / fmaxf(c1, 1e-6f);
  float r_c2 = 1.0f / fmaxf(c2, 1e-6f);

  float mis0 = v0[0] * r_is, mis1 = v1[0] * r_is;
  float mos0 = v0[1] * r_os, mos1 = v1[1] * r_os;
  float mil0 = v0[2] * r_il, mil1 = v1[2] * r_il;
  float mol0 = v0[3] * r_ol, mol1 = v1[3] * r_ol;
  float mhs0 = v0[4] * r_sm, mhs1 = v1[4] * r_sm;
  float mhl0 = v0[5] * r_lm, mhl1 = v1[5] * r_lm;
  float mh10 = h10 * r_c1, mh11 = h11 * r_c1;
  float mh20 = h20 * r_c2, mh21 = h21 * r_c2;

  LN2 z_burst = ln128(mis0 + mos0 - mil0 - mol0, mis1 + mos1 - mil1 - mol1);
  LN2 z_dgap  = ln128(mol0 - mil0, mol1 - mil1);
  LN2 z_hgap  = ln128(mh10 - mh20, mh11 - mh21);
  LN2 z_sl    = ln128(mhs0 - mhl0, mhs1 - mhl1);
  LN2 z_asym  = ln128(fabsf(z_dgap.zx), fabsf(z_dgap.zy));
  LN2 z_h1    = ln128(mh10, mh11);
  LN2 z_h2    = ln128(mh20, mh21);
  LN2 z_rb    = ln128(mil0 + mol0, mil1 + mol1);

  if (lane == 0) {
    normbuf[t] = z_hgap.norm;
    normbuf[TDIM + t] = z_sl.norm;
    normbuf[2 * TDIM + t] = z_dgap.norm;
  }

  float* frow = fused + (size_t)t * 1056;
  *(float2*)(frow + 0 * HDIM + co) = make_float2(z_burst.zx, z_burst.zy);
  *(float2*)(frow + 1 * HDIM + co) = make_float2(z_dgap.zx, z_dgap.zy);
  *(float2*)(frow + 2 * HDIM + co) = make_float2(z_hgap.zx, z_hgap.zy);
  *(float2*)(frow + 3 * HDIM + co) = make_float2(z_sl.zx, z_sl.zy);
  *(float2*)(frow + 4 * HDIM + co) = make_float2(z_asym.zx, z_asym.zy);
  *(float2*)(frow + 5 * HDIM + co) = make_float2(z_h1.zx, z_h1.zy);
  *(float2*)(frow + 6 * HDIM + co) = make_float2(z_h2.zx, z_h2.zy);
  *(float2*)(frow + 7 * HDIM + co) = make_float2(z_rb.zx, z_rb.zy);

  float ecf = (float)ec;
  float sf[8];
  sf[0] = log1pf(cin);
  sf[1] = log1pf(ecf - cin);
  sf[2] = log1pf(c1);
  sf[3] = log1pf(c2);
  sf[4] = tsum / fmaxf(ecf, 1e-6f);
  sf[5] = sm;
  sf[6] = lm;
  sf[7] = sm - lm;
  if (lane < 32) {
    float acc = b1[lane];
#pragma unroll
    for (int i = 0; i < 8; i++) acc += sf[i] * W1[i * 32 + lane];
    frow[1024 + lane] = gelu_exact(acc);
  }
}

// ---------------------------------------------------------------------------
// K5/K6: tiled fp32 GEMM  C[M,N] = epilogue(A[M,K] @ B[K,N] + bias)
// 32x64 tile, BK=32, 256 threads, 2x4 per-thread microtile.
// MODE 0: exact GELU. MODE 1: 0.25*tanh.
// ---------------------------------------------------------------------------
template <int MODE>
__global__ __launch_bounds__(256) void gemm_kernel(
    const float* __restrict__ A, const float* __restrict__ B,
    const float* __restrict__ bias, float* __restrict__ C,
    int M, int N, int K) {
  __shared__ __align__(16) float As[32][34];  // [k][m]
  __shared__ __align__(16) float Bs[32][68];  // [k][n]
  const int tid = threadIdx.x;
  const int tx = tid & 15, ty = tid >> 4;
  const int m0 = blockIdx.y * 32, n0 = blockIdx.x * 64;
  float acc[2][4] = {};

  const int am = tid >> 3;            // 0..31
  const int ak = (tid & 7) * 4;       // 0,4,..,28
  const int bk = tid >> 3;            // 0..31
  const int bn = (tid & 7) * 8;       // 0,8,..,56

  for (int kt = 0; kt < K; kt += 32) {
    float4 av = *(const float4*)&A[(size_t)(m0 + am) * K + kt + ak];
    const float* bp = &B[(size_t)(kt + bk) * N + n0 + bn];
    float4 bv0 = *(const float4*)bp;
    float4 bv1 = *(const float4*)(bp + 4);
    As[ak + 0][am] = av.x;
    As[ak + 1][am] = av.y;
    As[ak + 2][am] = av.z;
    As[ak + 3][am] = av.w;
    *(float4*)&Bs[bk][bn] = bv0;
    *(float4*)&Bs[bk][bn + 4] = bv1;
    __syncthreads();
#pragma unroll
    for (int kk = 0; kk < 32; kk++) {
      float2 a2 = *(const float2*)&As[kk][ty * 2];
      float4 b4 = *(const float4*)&Bs[kk][tx * 4];
      float a[2] = {a2.x, a2.y};
      float b[4] = {b4.x, b4.y, b4.z, b4.w};
#pragma unroll
      for (int i2 = 0; i2 < 2; i2++)
#pragma unroll
        for (int j2 = 0; j2 < 4; j2++)
          acc[i2][j2] = fmaf(a[i2], b[j2], acc[i2][j2]);
    }
    __syncthreads();
  }

#pragma unroll
  for (int i2 = 0; i2 < 2; i2++) {
    int m = m0 + ty * 2 + i2;
    int n = n0 + tx * 4;
    float4 bb = *(const float4*)&bias[n];
    float4 v;
    v.x = acc[i2][0] + bb.x;
    v.y = acc[i2][1] + bb.y;
    v.z = acc[i2][2] + bb.z;
    v.w = acc[i2][3] + bb.w;
    if (MODE == 0) {
      v.x = gelu_exact(v.x); v.y = gelu_exact(v.y);
      v.z = gelu_exact(v.z); v.w = gelu_exact(v.w);
    } else {
      v.x = 0.25f * tanhf(v.x); v.y = 0.25f * tanhf(v.y);
      v.z = 0.25f * tanhf(v.z); v.w = 0.25f * tanhf(v.w);
    }
    *(float4*)&C[(size_t)m * N + n] = v;
  }
}

// ---------------------------------------------------------------------------
// K7: tree-reduce per-target norms -> output tail
// ---------------------------------------------------------------------------
__global__ __launch_bounds__(256) void finalize_kernel(
    const float* __restrict__ normbuf, float* __restrict__ out) {
  const int tid = threadIdx.x;
  const int w = tid >> 6, lane = tid & 63;
  float s0 = 0, s1 = 0, s2 = 0;
  for (int t = tid; t < TDIM; t += 256) {
    s0 += normbuf[t];
    s1 += normbuf[TDIM + t];
    s2 += normbuf[2 * TDIM + t];
  }
  s0 = wave_sum64(s0);
  s1 = wave_sum64(s1);
  s2 = wave_sum64(s2);
  __shared__ float red[3][4];
  if (lane == 0) { red[0][w] = s0; red[1][w] = s1; red[2][w] = s2; }
  __syncthreads();
  if (tid < 3) {
    float v = red[tid][0] + red[tid][1] + red[tid][2] + red[tid][3];
    out[(size_t)TDIM * HDIM + tid] = v * (1.0f / (float)TDIM);
  }
}

// ---------------------------------------------------------------------------
extern "C" void kernel_launch(void* const* d_in, const int* in_sizes, int n_in,
                              void* d_out, int out_size, void* d_ws, size_t ws_size,
                              hipStream_t stream) {
  const float* node_repr = (const float*)d_in[0];
  const float* edge_repr = (const float*)d_in[1];
  const int* edge_src = (const int*)d_in[2];
  const int* edge_dst = (const int*)d_in[3];
  const int* rel_ids = (const int*)d_in[4];
  const float* etime = (const float*)d_in[5];
  const int* tli = (const int*)d_in[6];
  const int* nsg = (const int*)d_in[7];
  const int* esg = (const int*)d_in[8];
  const int* depth = (const int*)d_in[9];
  const float* W1 = (const float*)d_in[10];
  const float* b1 = (const float*)d_in[11];
  const float* W2 = (const float*)d_in[12];
  const float* b2 = (const float*)d_in[13];
  const float* W3 = (const float*)d_in[14];
  const float* b3 = (const float*)d_in[15];
  float* out = (float*)d_out;

  const int E_ = in_sizes[2];
  const int N_ = in_sizes[7];

  char* ws = (char*)d_ws;
  size_t off = 0;
  auto alloc = [&](size_t bytes) -> void* {
    off = (off + 255) & ~(size_t)255;
    void* p = ws + off;
    off += bytes;
    return p;
  };
  int* ecnt = (int*)alloc((size_t)TDIM * 4);
  int* eoff = (int*)alloc((size_t)TDIM * 4);
  int* ecur = (int*)alloc((size_t)TDIM * 4);
  int* ncnt = (int*)alloc((size_t)TDIM * 4);
  int* noff = (int*)alloc((size_t)TDIM * 4);
  int* ncur = (int*)alloc((size_t)TDIM * 4);
  int* s_eid = (int*)alloc((size_t)E_ * 4);
  int* s_srcpk = (int*)alloc((size_t)E_ * 4);
  float* s_t = (float*)alloc((size_t)E_ * 4);
  int* s_npk = (int*)alloc((size_t)N_ * 4);
  float* fused = (float*)alloc((size_t)TDIM * 1056 * 4);
  float* hidden = (float*)alloc((size_t)TDIM * 256 * 4);
  float* normbuf = (float*)alloc((size_t)3 * TDIM * 4);

  hipMemsetAsync(ecnt, 0, (size_t)TDIM * 4, stream);
  hipMemsetAsync(ncnt, 0, (size_t)TDIM * 4, stream);

  int gmax = (E_ > N_ ? E_ : N_);
  int g1 = (gmax + 255) / 256;

  count_kernel<<<g1, 256, 0, stream>>>(edge_dst, esg, tli, nsg, ecnt, ncnt, E_, N_);
  scan_kernel<<<2, 64, 0, stream>>>(ecnt, eoff, ecur, ncnt, noff, ncur);
  scatter_kernel<<<g1, 256, 0, stream>>>(edge_dst, esg, tli, edge_src, rel_ids,
                                         etime, nsg, depth, ecur, ncur,
                                         s_eid, s_srcpk, s_t, s_npk, E_, N_);
  target_kernel<<<TDIM, 256, 0, stream>>>(node_repr, edge_repr, eoff, ecnt, noff,
                                          ncnt, s_eid, s_srcpk, s_t, s_npk,
                                          W1, b1, fused, normbuf);
  gemm_kernel<0><<<dim3(256 / 64, TDIM / 32), 256, 0, stream>>>(
      fused, W2, b2, hidden, TDIM, 256, 8 * HDIM + 32);
  gemm_kernel<1><<<dim3(HDIM / 64, TDIM / 32), 256, 0, stream>>>(
      hidden, W3, b3, out, TDIM, HDIM, 256);
  finalize_kernel<<<1, 256, 0, stream>>>(normbuf, out);
}